// Round 2
// baseline (1036.653 us; speedup 1.0000x reference)
//
#include <hip/hip_runtime.h>
#include <hip/hip_bf16.h>
#include <stdint.h>

#define BATCH  1024
#define DIM    1024
#define NKH    65536
#define NKEYS  4096
#define HID    1024

// (BETA / sqrt(DIM)) * log2(e) = 0.25 * 1.4426950408889634
#define SC1 0.36067376022224085f

typedef __bf16 bf16x8 __attribute__((ext_vector_type(8)));
typedef float  f32x4  __attribute__((ext_vector_type(4)));

__device__ __forceinline__ unsigned short f2bf(float f) {
  union { float f; unsigned int u; } v; v.f = f;
  unsigned int r = v.u + 0x7fffu + ((v.u >> 16) & 1u);
  return (unsigned short)(r >> 16);
}
__device__ __forceinline__ float bf2f(unsigned short s) {
  union { unsigned int u; float f; } v; v.u = ((unsigned int)s) << 16;
  return v.f;
}
__device__ __forceinline__ unsigned int pk2(float lo, float hi) {
  union { __hip_bfloat162 h; unsigned int u; } v;
  v.h = __float22bfloat162_rn(make_float2(lo, hi));
  return v.u;
}
__device__ __forceinline__ void gl2lds16(const void* g, void* l) {
  __builtin_amdgcn_global_load_lds(
      (const __attribute__((address_space(1))) void*)g,
      (__attribute__((address_space(3))) void*)l, 16, 0, 0);
}

// ---------------------------------------------------------------------------
// Fused cast: keys (with head-major row permute n=k*16+h -> n'=h*4096+k) and
// x (plain). keys span = NKH*DIM/8 / 256 = 32768 blocks exactly, so the
// branch is block-uniform (no divergence).
// ---------------------------------------------------------------------------
#define KEY_GROUPS (NKH * (DIM / 8))        // 8388608, /256 = 32768 blocks
__global__ __launch_bounds__(256) void k_cast_all(
    const float* __restrict__ keys, const float* __restrict__ x,
    unsigned short* __restrict__ Kb, unsigned short* __restrict__ Xb) {
  int i = blockIdx.x * 256 + threadIdx.x;
  if (i < KEY_GROUPS) {
    int row = i >> 7, seg = i & 127;          // DIM/8 = 128 groups per row
    int n2 = ((row & 15) << 12) | (row >> 4); // h*4096 + k
    float4 a = ((const float4*)keys)[(size_t)i * 2];
    float4 b = ((const float4*)keys)[(size_t)i * 2 + 1];
    uint4 o;
    o.x = pk2(a.x, a.y); o.y = pk2(a.z, a.w);
    o.z = pk2(b.x, b.y); o.w = pk2(b.z, b.w);
    ((uint4*)Kb)[((size_t)n2 << 7) | seg] = o;
  } else {
    int j = i - KEY_GROUPS;
    if (j < BATCH * (DIM / 8)) {
      float4 a = ((const float4*)x)[(size_t)j * 2];
      float4 b = ((const float4*)x)[(size_t)j * 2 + 1];
      uint4 o;
      o.x = pk2(a.x, a.y); o.y = pk2(a.z, a.w);
      o.z = pk2(b.x, b.y); o.w = pk2(b.z, b.w);
      ((uint4*)Xb)[j] = o;
    }
  }
}

// ---------------------------------------------------------------------------
// values [65536,1024] fp32 -> vT [1024,65536] bf16, transposed AND head-major
// permuted on the n axis: vT[j, h*4096+k] = values[k*16+h, j].
// ---------------------------------------------------------------------------
__global__ __launch_bounds__(256) void k_transpose_cast(
    const float* __restrict__ V, unsigned short* __restrict__ vT) {
  __shared__ float tile[64][65];  // +1 pad: conflict-free transposed reads
  const int t = threadIdx.x;
  const int nk0 = blockIdx.x * 64;           // output column base (n' space)
  const int h   = blockIdx.x >> 6;           // nk0 / 4096 (64 | 4096, aligned)
  const int k0  = (blockIdx.x & 63) * 64;    // nk0 % 4096
  const int j0  = blockIdx.y * 64;
  #pragma unroll
  for (int i = 0; i < 4; ++i) {
    int idx = t + i * 256;
    int row = idx >> 4, c4 = (idx & 15) << 2;
    // source V row for output column nk0+row:  (k0+row)*16 + h
    float4 v = *(const float4*)(V + (size_t)((k0 + row) * 16 + h) * HID + (j0 + c4));
    tile[row][c4 + 0] = v.x; tile[row][c4 + 1] = v.y;
    tile[row][c4 + 2] = v.z; tile[row][c4 + 3] = v.w;
  }
  __syncthreads();
  const int q = t & 7, jj = t >> 3;
  #pragma unroll
  for (int i = 0; i < 2; ++i) {
    int j = jj + i * 32;
    uint4 o;
    o.x = pk2(tile[q*8+0][j], tile[q*8+1][j]);
    o.y = pk2(tile[q*8+2][j], tile[q*8+3][j]);
    o.z = pk2(tile[q*8+4][j], tile[q*8+5][j]);
    o.w = pk2(tile[q*8+6][j], tile[q*8+7][j]);
    *(uint4*)(vT + (size_t)(j0 + j) * NKH + (nk0 + q*8)) = o;
  }
}

// ---------------------------------------------------------------------------
// GEMM1: E[b,n'] = exp2(SC1 * x[b,:]·keys'[n',:])  (bf16 in, bf16 out)
// m97 structure: global_load_lds width-16, 128x128 tile, BK=32, 4 waves 2x2.
// FUSED: per-(row,head) denominator partials -> atomicAdd into denom[B,16].
// Each 128-col block lies in exactly one head (head-major layout, 128|4096).
// No XCD swizzle here: read set (134MB Kb + 2MB Xb) is L3-resident (m160:
// swizzle costs ~2% when L3-fit).
// ---------------------------------------------------------------------------
__global__ __launch_bounds__(256) void k_gemm1_exp(
    const unsigned short* __restrict__ Xb, const unsigned short* __restrict__ Kb,
    unsigned short* __restrict__ E, float* __restrict__ denom) {
  __shared__ __align__(16) unsigned short As[128 * 32];
  __shared__ __align__(16) unsigned short Bs[128 * 32];
  __shared__ float dsum[128];
  const int t = threadIdx.x;
  const int bm = blockIdx.x & 7, bn = blockIdx.x >> 3;  // bm fastest: 8 blocks share B-tile
  const int m0 = bm << 7, n0 = bn << 7;
  const int lane = t & 63, wave = t >> 6;
  const int wm = (wave >> 1) << 6, wn = (wave & 1) << 6;
  const int r16 = lane & 15, quad = lane >> 4;
  const int srow = lane >> 2, kseg = (lane & 3) * 8;
  const int c0 = wave * 2, c1 = wave * 2 + 1;
  const unsigned short* gA0 = Xb + (size_t)(m0 + c0*16 + srow) * DIM + kseg;
  const unsigned short* gA1 = Xb + (size_t)(m0 + c1*16 + srow) * DIM + kseg;
  const unsigned short* gB0 = Kb + (size_t)(n0 + c0*16 + srow) * DIM + kseg;
  const unsigned short* gB1 = Kb + (size_t)(n0 + c1*16 + srow) * DIM + kseg;
  if (t < 128) dsum[t] = 0.0f;   // first in-loop __syncthreads orders this
  f32x4 acc[4][4] = {};
  for (int ks = 0; ks < DIM; ks += 32) {
    __syncthreads();
    gl2lds16(gA0 + ks, As + c0 * 512);
    gl2lds16(gA1 + ks, As + c1 * 512);
    gl2lds16(gB0 + ks, Bs + c0 * 512);
    gl2lds16(gB1 + ks, Bs + c1 * 512);
    __syncthreads();
    bf16x8 af[4], bfr[4];
    #pragma unroll
    for (int mi = 0; mi < 4; ++mi)
      af[mi] = *(const bf16x8*)(As + (wm + mi*16 + r16) * 32 + quad * 8);
    #pragma unroll
    for (int ni = 0; ni < 4; ++ni)
      bfr[ni] = *(const bf16x8*)(Bs + (wn + ni*16 + r16) * 32 + quad * 8);
    #pragma unroll
    for (int mi = 0; mi < 4; ++mi)
      #pragma unroll
      for (int ni = 0; ni < 4; ++ni)
        acc[mi][ni] = __builtin_amdgcn_mfma_f32_16x16x32_bf16(af[mi], bfr[ni], acc[mi][ni], 0, 0, 0);
  }
  // C/D layout: col = lane&15, row = quad*4 + reg
  float rs[16] = {0,0,0,0,0,0,0,0,0,0,0,0,0,0,0,0};  // [mi*4+v] row partials
  #pragma unroll
  for (int mi = 0; mi < 4; ++mi) {
    #pragma unroll
    for (int ni = 0; ni < 4; ++ni) {
      #pragma unroll
      for (int v = 0; v < 4; ++v) {
        float e = exp2f(acc[mi][ni][v] * SC1);
        int row = m0 + wm + mi*16 + quad*4 + v;
        int col = n0 + wn + ni*16 + r16;
        E[(size_t)row * NKH + col] = f2bf(e);
        rs[mi*4 + v] += e;
      }
    }
  }
  // reduce across the 16 lanes of each quad group (cols), then LDS, then global
  #pragma unroll
  for (int m = 1; m < 16; m <<= 1)
    #pragma unroll
    for (int i = 0; i < 16; ++i) rs[i] += __shfl_xor(rs[i], m);
  if (r16 == 0) {
    #pragma unroll
    for (int i = 0; i < 16; ++i)
      atomicAdd(&dsum[wm + (i >> 2)*16 + quad*4 + (i & 3)], rs[i]);
  }
  __syncthreads();
  const int h = n0 >> 12;  // head of this column block
  if (t < 128) atomicAdd(&denom[(size_t)(m0 + t) * 16 + h], dsum[t]);
}

// ---------------------------------------------------------------------------
// GEMM2: out[b,j] += (1/denom[b,sp]) * sum_n E[b,n] * vT[j,n]
// split-K = 16 aligned on heads (4096 each) -> scale folds into the epilogue.
// XCD swizzle: read set (134MB E + 134MB vT) exceeds 256MB L3 -> HBM-bound
// regime where T1 measured +10%. Chunk per XCD = 128 logical blocks = exactly
// 2 head-groups, confining each head's 16MB slice to one L2. 1024%8==0 ->
// simple swizzle is bijective.
// ---------------------------------------------------------------------------
__global__ __launch_bounds__(256) void k_gemm2(
    const unsigned short* __restrict__ P, const unsigned short* __restrict__ Vt,
    float* __restrict__ out, const float* __restrict__ denom) {
  __shared__ __align__(16) unsigned short As[128 * 32];
  __shared__ __align__(16) unsigned short Bs[128 * 32];
  const int t = threadIdx.x;
  const int nwg = 1024, cpx = nwg >> 3;  // 8*8*16 blocks, 128 per XCD
  const int lb = (blockIdx.x & 7) * cpx + (blockIdx.x >> 3);  // bijective
  const int bm = lb & 7, bn = (lb >> 3) & 7, sp = lb >> 6;
  const int m0 = bm << 7, n0 = bn << 7;
  const size_t kb = (size_t)sp * (NKH / 16);  // head sp's K-range
  const int lane = t & 63, wave = t >> 6;
  const int wm = (wave >> 1) << 6, wn = (wave & 1) << 6;
  const int r16 = lane & 15, quad = lane >> 4;
  const int srow = lane >> 2, kseg = (lane & 3) * 8;
  const int c0 = wave * 2, c1 = wave * 2 + 1;
  const unsigned short* gA0 = P  + (size_t)(m0 + c0*16 + srow) * NKH + kb + kseg;
  const unsigned short* gA1 = P  + (size_t)(m0 + c1*16 + srow) * NKH + kb + kseg;
  const unsigned short* gB0 = Vt + (size_t)(n0 + c0*16 + srow) * NKH + kb + kseg;
  const unsigned short* gB1 = Vt + (size_t)(n0 + c1*16 + srow) * NKH + kb + kseg;
  f32x4 acc[4][4] = {};
  for (int ks = 0; ks < NKH / 16; ks += 32) {
    __syncthreads();
    gl2lds16(gA0 + ks, As + c0 * 512);
    gl2lds16(gA1 + ks, As + c1 * 512);
    gl2lds16(gB0 + ks, Bs + c0 * 512);
    gl2lds16(gB1 + ks, Bs + c1 * 512);
    __syncthreads();
    bf16x8 af[4], bfr[4];
    #pragma unroll
    for (int mi = 0; mi < 4; ++mi)
      af[mi] = *(const bf16x8*)(As + (wm + mi*16 + r16) * 32 + quad * 8);
    #pragma unroll
    for (int ni = 0; ni < 4; ++ni)
      bfr[ni] = *(const bf16x8*)(Bs + (wn + ni*16 + r16) * 32 + quad * 8);
    #pragma unroll
    for (int mi = 0; mi < 4; ++mi)
      #pragma unroll
      for (int ni = 0; ni < 4; ++ni)
        acc[mi][ni] = __builtin_amdgcn_mfma_f32_16x16x32_bf16(af[mi], bfr[ni], acc[mi][ni], 0, 0, 0);
  }
  #pragma unroll
  for (int mi = 0; mi < 4; ++mi) {
    float rr[4];
    #pragma unroll
    for (int v = 0; v < 4; ++v) {
      int row = m0 + wm + mi*16 + quad*4 + v;
      rr[v] = 1.0f / denom[(size_t)row * 16 + sp];
    }
    #pragma unroll
    for (int ni = 0; ni < 4; ++ni) {
      #pragma unroll
      for (int v = 0; v < 4; ++v) {
        int row = m0 + wm + mi*16 + quad*4 + v;
        int col = n0 + wn + ni*16 + r16;
        unsafeAtomicAdd(&out[(size_t)row * HID + col], acc[mi][ni][v] * rr[v]);
      }
    }
  }
}

extern "C" void kernel_launch(void* const* d_in, const int* in_sizes, int n_in,
                              void* d_out, int out_size, void* d_ws, size_t ws_size,
                              hipStream_t stream) {
  (void)in_sizes; (void)n_in; (void)out_size; (void)ws_size;
  const float* x      = (const float*)d_in[0];
  const float* keys   = (const float*)d_in[1];
  const float* values = (const float*)d_in[2];
  float* out = (float*)d_out;

  // ws layout: E [1024*65536] bf16 | B2 [65536*1024] bf16 (Kb', later vT') |
  //            Xb [1024*1024] bf16 | denom [1024*16] f32   (~270 MB total)
  unsigned short* E  = (unsigned short*)d_ws;
  unsigned short* B2 = E + (size_t)BATCH * NKH;
  unsigned short* Xb = B2 + (size_t)NKH * DIM;
  float* denom = (float*)(Xb + (size_t)BATCH * DIM);

  hipMemsetAsync(d_out, 0, (size_t)BATCH * HID * sizeof(float), stream);
  hipMemsetAsync(denom, 0, (size_t)BATCH * 16 * sizeof(float), stream);
  k_cast_all<<<(KEY_GROUPS + BATCH * (DIM / 8) + 255) / 256, 256, 0, stream>>>(
      keys, x, B2, Xb);
  k_gemm1_exp<<<(BATCH / 128) * (NKH / 128), 256, 0, stream>>>(Xb, B2, E, denom);
  // B2 now free (gemm1 done): reuse it for head-major vT
  k_transpose_cast<<<dim3(NKH / 64, HID / 64), 256, 0, stream>>>(values, B2);
  k_gemm2<<<(BATCH / 128) * (HID / 128) * 16, 256, 0, stream>>>(E, B2, out, denom);
}

// Round 3
// 985.357 us; speedup vs baseline: 1.0521x; 1.0521x over previous
//
#include <hip/hip_runtime.h>
#include <hip/hip_bf16.h>
#include <stdint.h>

#define BATCH  1024
#define DIM    1024
#define NKH    65536
#define NKEYS  4096
#define HID    1024

// (BETA / sqrt(DIM)) * log2(e) = 0.25 * 1.4426950408889634
#define SC1 0.36067376022224085f

typedef __bf16 bf16x8 __attribute__((ext_vector_type(8)));
typedef float  f32x4  __attribute__((ext_vector_type(4)));

__device__ __forceinline__ unsigned short f2bf(float f) {
  union { float f; unsigned int u; } v; v.f = f;
  unsigned int r = v.u + 0x7fffu + ((v.u >> 16) & 1u);
  return (unsigned short)(r >> 16);
}
__device__ __forceinline__ unsigned int pk2(float lo, float hi) {
  union { __hip_bfloat162 h; unsigned int u; } v;
  v.h = __float22bfloat162_rn(make_float2(lo, hi));
  return v.u;
}
__device__ __forceinline__ void gl2lds16(const void* g, void* l) {
  __builtin_amdgcn_global_load_lds(
      (const __attribute__((address_space(1))) void*)g,
      (__attribute__((address_space(3))) void*)l, 16, 0, 0);
}

// ---------------------------------------------------------------------------
// Fused cast: keys (head-major permute n=k*16+h -> n'=h*4096+k), x (plain),
// and denom zeroing. All branch boundaries are exact block multiples.
// ---------------------------------------------------------------------------
#define KEY_GROUPS (NKH * (DIM / 8))          // 8388608 -> 32768 blocks
#define X_GROUPS   (BATCH * (DIM / 8))        // 131072  -> 512 blocks
#define DN_GROUPS  (BATCH * 16 / 4)           // 4096    -> 16 blocks
__global__ __launch_bounds__(256) void k_cast_all(
    const float* __restrict__ keys, const float* __restrict__ x,
    unsigned short* __restrict__ Kb, unsigned short* __restrict__ Xb,
    float* __restrict__ denom) {
  int i = blockIdx.x * 256 + threadIdx.x;
  if (i < KEY_GROUPS) {
    int row = i >> 7, seg = i & 127;
    int n2 = ((row & 15) << 12) | (row >> 4);  // h*4096 + k
    float4 a = ((const float4*)keys)[(size_t)i * 2];
    float4 b = ((const float4*)keys)[(size_t)i * 2 + 1];
    uint4 o;
    o.x = pk2(a.x, a.y); o.y = pk2(a.z, a.w);
    o.z = pk2(b.x, b.y); o.w = pk2(b.z, b.w);
    ((uint4*)Kb)[((size_t)n2 << 7) | seg] = o;
  } else if (i < KEY_GROUPS + X_GROUPS) {
    int j = i - KEY_GROUPS;
    float4 a = ((const float4*)x)[(size_t)j * 2];
    float4 b = ((const float4*)x)[(size_t)j * 2 + 1];
    uint4 o;
    o.x = pk2(a.x, a.y); o.y = pk2(a.z, a.w);
    o.z = pk2(b.x, b.y); o.w = pk2(b.z, b.w);
    ((uint4*)Xb)[j] = o;
  } else {
    int d = i - KEY_GROUPS - X_GROUPS;
    if (d < DN_GROUPS) ((float4*)denom)[d] = make_float4(0.f, 0.f, 0.f, 0.f);
  }
}

// ---------------------------------------------------------------------------
// values -> vT (transposed, head-major) fused with zeroing of out.
// blocks [0,16384): transpose; [16384, 17408): zero out (4 MB).
// ---------------------------------------------------------------------------
__global__ __launch_bounds__(256) void k_fuse_vt(
    const float* __restrict__ V, unsigned short* __restrict__ vT,
    float* __restrict__ out) {
  const int bid = blockIdx.x;
  const int t = threadIdx.x;
  if (bid >= 16384) {
    int zi = (bid - 16384) * 256 + t;  // float4 index, 262144 total
    ((float4*)out)[zi] = make_float4(0.f, 0.f, 0.f, 0.f);
    return;
  }
  __shared__ float tile[64][65];
  const int bx = bid & 1023, by = bid >> 10;
  const int nk0 = bx * 64;
  const int h   = bx >> 6;
  const int k0  = (bx & 63) * 64;
  const int j0  = by * 64;
  #pragma unroll
  for (int i = 0; i < 4; ++i) {
    int idx = t + i * 256;
    int row = idx >> 4, c4 = (idx & 15) << 2;
    float4 v = *(const float4*)(V + (size_t)((k0 + row) * 16 + h) * HID + (j0 + c4));
    tile[row][c4 + 0] = v.x; tile[row][c4 + 1] = v.y;
    tile[row][c4 + 2] = v.z; tile[row][c4 + 3] = v.w;
  }
  __syncthreads();
  const int q = t & 7, jj = t >> 3;
  #pragma unroll
  for (int i = 0; i < 2; ++i) {
    int j = jj + i * 32;
    uint4 o;
    o.x = pk2(tile[q*8+0][j], tile[q*8+1][j]);
    o.y = pk2(tile[q*8+2][j], tile[q*8+3][j]);
    o.z = pk2(tile[q*8+4][j], tile[q*8+5][j]);
    o.w = pk2(tile[q*8+6][j], tile[q*8+7][j]);
    *(uint4*)(vT + (size_t)(j0 + j) * NKH + (nk0 + q*8)) = o;
  }
}

// ---------------------------------------------------------------------------
// Pipelined 256x256xBK64 GEMM core. 8 waves (2M x 4N), dbuf LDS, 4 phases per
// K-tile, counted vmcnt(4) (never drains), raw s_barrier, row-XOR LDS swizzle
// applied both-sides (pre-swizzled global src for linear global_load_lds +
// swizzled ds_read).  Phase p stages exactly the half-tile consumed at phase p
// of the NEXT K-tile:  P1: A-lo + reads(A-lo,B-lo); P2: B-lo + reads(B-hi);
// P3: B-hi + reads(A-hi); P4: A-hi + no reads.
//   Half-tile row sets (aligned to per-wave reads):
//     A-lo = rows {0-63, 128-191}, A-hi = {64-127, 192-255}
//     B-lo = rows {wc*64+[0,32)},  B-hi = {wc*64+[32,64)}
// ---------------------------------------------------------------------------
#define PH_WAIT4 do { asm volatile("s_waitcnt vmcnt(4)" ::: "memory"); \
                      __builtin_amdgcn_s_barrier();                    \
                      asm volatile("" ::: "memory"); } while (0)
#define PH_BAR   do { __builtin_amdgcn_s_barrier();                    \
                      asm volatile("" ::: "memory"); } while (0)

__device__ __forceinline__ void gemm_core(
    const unsigned short* __restrict__ A, const unsigned short* __restrict__ B,
    size_t lda, size_t ldb, int m0, int n0, size_t k0, int nt,
    unsigned short* As, unsigned short* Bs, f32x4 (&acc)[8][4]) {
  const int t = threadIdx.x, lane = t & 63, w = t >> 6;
  const int wr = w >> 2, wc = w & 3;
  const int r16 = lane & 15, quad = lane >> 4;
  const int srow = (w << 3) + (lane >> 3);              // 0..63
  const int ksl  = (((lane & 7) ^ (lane >> 3)) << 3);   // pre-swizzled k slot
  const int e8   = r16 & 7;
  const int sq0  = ((quad ^ e8) << 3);                  // ds_read slot, kk=0
  const int sq1  = (((4 + quad) ^ e8) << 3);            // ds_read slot, kk=1
  // per-lane global bases [h][l]
  const unsigned short* Ag[2][2];
  const unsigned short* Bg[2][2];
  const int bsw = srow + (srow & 32);  // B row perm within half
  #pragma unroll
  for (int h = 0; h < 2; ++h)
    #pragma unroll
    for (int l = 0; l < 2; ++l) {
      Ag[h][l] = A + (size_t)(m0 + h*64 + l*128 + srow) * lda + k0 + ksl;
      Bg[h][l] = B + (size_t)(n0 + h*32 + l*128 + bsw)  * ldb + k0 + ksl;
    }
  // wave-uniform LDS dest offsets (ushorts)
  const int wrow = w << 3;
  const int boff = wrow + ((w >= 4) ? 32 : 0);
  const int dAr[2][2] = {{ (wrow)*64,      (128 + wrow)*64 },
                         { (64 + wrow)*64, (192 + wrow)*64 }};
  const int dBr[2][2] = {{ (boff)*64,      (128 + boff)*64 },
                         { (32 + boff)*64, (160 + boff)*64 }};
  // prologue: stage tile 0 into buf0, in steady-state issue order
  gl2lds16(Ag[0][0], As + dAr[0][0]); gl2lds16(Ag[0][1], As + dAr[0][1]);
  gl2lds16(Bg[0][0], Bs + dBr[0][0]); gl2lds16(Bg[0][1], Bs + dBr[0][1]);
  gl2lds16(Bg[1][0], Bs + dBr[1][0]); gl2lds16(Bg[1][1], Bs + dBr[1][1]);
  gl2lds16(Ag[1][0], As + dAr[1][0]); gl2lds16(Ag[1][1], As + dAr[1][1]);

  bf16x8 am[4][2], bn_[4][2];
  for (int tt = 0; tt < nt; ++tt) {
    unsigned short* Asc = As + ((tt & 1) << 14);
    unsigned short* Bsc = Bs + ((tt & 1) << 14);
    unsigned short* Asn = As + ((~tt & 1) << 14);
    unsigned short* Bsn = Bs + ((~tt & 1) << 14);
    const size_t kn = (size_t)((tt + 1 < nt) ? (tt + 1) : tt) * 64;  // clamped
    // ---- P1: stage A-lo(t+1); read A-lo, B-lo; mfma q1 ----
    PH_WAIT4;
    gl2lds16(Ag[0][0] + kn, Asn + dAr[0][0]);
    gl2lds16(Ag[0][1] + kn, Asn + dAr[0][1]);
    #pragma unroll
    for (int mi = 0; mi < 4; ++mi) {
      const unsigned short* p = Asc + (wr*128 + mi*16 + r16) * 64;
      am[mi][0] = *(const bf16x8*)(p + sq0);
      am[mi][1] = *(const bf16x8*)(p + sq1);
    }
    #pragma unroll
    for (int ni = 0; ni < 2; ++ni) {
      const unsigned short* p = Bsc + (wc*64 + ni*16 + r16) * 64;
      bn_[ni][0] = *(const bf16x8*)(p + sq0);
      bn_[ni][1] = *(const bf16x8*)(p + sq1);
    }
    __builtin_amdgcn_s_setprio(1);
    #pragma unroll
    for (int mi = 0; mi < 4; ++mi)
      #pragma unroll
      for (int ni = 0; ni < 2; ++ni) {
        acc[mi][ni] = __builtin_amdgcn_mfma_f32_16x16x32_bf16(am[mi][0], bn_[ni][0], acc[mi][ni], 0, 0, 0);
        acc[mi][ni] = __builtin_amdgcn_mfma_f32_16x16x32_bf16(am[mi][1], bn_[ni][1], acc[mi][ni], 0, 0, 0);
      }
    __builtin_amdgcn_s_setprio(0);
    // ---- P2: stage B-lo(t+1); read B-hi; mfma q2 ----
    PH_WAIT4;
    gl2lds16(Bg[0][0] + kn, Bsn + dBr[0][0]);
    gl2lds16(Bg[0][1] + kn, Bsn + dBr[0][1]);
    #pragma unroll
    for (int ni = 2; ni < 4; ++ni) {
      const unsigned short* p = Bsc + (wc*64 + ni*16 + r16) * 64;
      bn_[ni][0] = *(const bf16x8*)(p + sq0);
      bn_[ni][1] = *(const bf16x8*)(p + sq1);
    }
    __builtin_amdgcn_s_setprio(1);
    #pragma unroll
    for (int mi = 0; mi < 4; ++mi)
      #pragma unroll
      for (int ni = 2; ni < 4; ++ni) {
        acc[mi][ni] = __builtin_amdgcn_mfma_f32_16x16x32_bf16(am[mi][0], bn_[ni][0], acc[mi][ni], 0, 0, 0);
        acc[mi][ni] = __builtin_amdgcn_mfma_f32_16x16x32_bf16(am[mi][1], bn_[ni][1], acc[mi][ni], 0, 0, 0);
      }
    __builtin_amdgcn_s_setprio(0);
    // ---- P3: stage B-hi(t+1); read A-hi; mfma q3 ----
    PH_WAIT4;
    gl2lds16(Bg[1][0] + kn, Bsn + dBr[1][0]);
    gl2lds16(Bg[1][1] + kn, Bsn + dBr[1][1]);
    #pragma unroll
    for (int mi = 0; mi < 4; ++mi) {
      const unsigned short* p = Asc + (wr*128 + 64 + mi*16 + r16) * 64;
      am[mi][0] = *(const bf16x8*)(p + sq0);
      am[mi][1] = *(const bf16x8*)(p + sq1);
    }
    __builtin_amdgcn_s_setprio(1);
    #pragma unroll
    for (int mi = 0; mi < 4; ++mi)
      #pragma unroll
      for (int ni = 0; ni < 2; ++ni) {
        acc[mi+4][ni] = __builtin_amdgcn_mfma_f32_16x16x32_bf16(am[mi][0], bn_[ni][0], acc[mi+4][ni], 0, 0, 0);
        acc[mi+4][ni] = __builtin_amdgcn_mfma_f32_16x16x32_bf16(am[mi][1], bn_[ni][1], acc[mi+4][ni], 0, 0, 0);
      }
    __builtin_amdgcn_s_setprio(0);
    // ---- P4: stage A-hi(t+1); mfma q4 (regs only) ----
    PH_BAR;
    gl2lds16(Ag[1][0] + kn, Asn + dAr[1][0]);
    gl2lds16(Ag[1][1] + kn, Asn + dAr[1][1]);
    __builtin_amdgcn_s_setprio(1);
    #pragma unroll
    for (int mi = 0; mi < 4; ++mi)
      #pragma unroll
      for (int ni = 2; ni < 4; ++ni) {
        acc[mi+4][ni] = __builtin_amdgcn_mfma_f32_16x16x32_bf16(am[mi][0], bn_[ni][0], acc[mi+4][ni], 0, 0, 0);
        acc[mi+4][ni] = __builtin_amdgcn_mfma_f32_16x16x32_bf16(am[mi][1], bn_[ni][1], acc[mi+4][ni], 0, 0, 0);
      }
    __builtin_amdgcn_s_setprio(0);
  }
}

// ---------------------------------------------------------------------------
// GEMM1: E[b,n'] = exp2(SC1 * x.keys'), fused per-(row,head) denominator.
// 256x256 tile, head = bn>>4 (256 | 4096 -> one head per block).
// ---------------------------------------------------------------------------
__global__ __launch_bounds__(512, 2) void k_gemm1_exp(
    const unsigned short* __restrict__ Xb, const unsigned short* __restrict__ Kb,
    unsigned short* __restrict__ E, float* __restrict__ denom) {
  __shared__ __align__(16) unsigned short As[2 * 16384];
  __shared__ __align__(16) unsigned short Bs[2 * 16384];
  __shared__ float dsum[256];
  const int t = threadIdx.x;
  const int bm = blockIdx.x & 3, bn = blockIdx.x >> 2;
  const int m0 = bm << 8, n0 = bn << 8;
  if (t < 256) dsum[t] = 0.0f;  // ordered before use by loop barriers
  f32x4 acc[8][4] = {};
  gemm_core(Xb, Kb, DIM, DIM, m0, n0, 0, DIM / 64, As, Bs, acc);
  const int lane = t & 63, w = t >> 6, wr = w >> 2, wc = w & 3;
  const int r16 = lane & 15, quad = lane >> 4;
  float rs[8][4];
  #pragma unroll
  for (int mi = 0; mi < 8; ++mi)
    #pragma unroll
    for (int v = 0; v < 4; ++v) rs[mi][v] = 0.0f;
  #pragma unroll
  for (int mi = 0; mi < 8; ++mi) {
    #pragma unroll
    for (int ni = 0; ni < 4; ++ni) {
      #pragma unroll
      for (int v = 0; v < 4; ++v) {
        float e = exp2f(acc[mi][ni][v] * SC1);
        int row = m0 + wr*128 + mi*16 + quad*4 + v;
        int col = n0 + wc*64 + ni*16 + r16;
        E[(size_t)row * NKH + col] = f2bf(e);
        rs[mi][v] += e;
      }
    }
  }
  #pragma unroll
  for (int m = 1; m < 16; m <<= 1)
    #pragma unroll
    for (int mi = 0; mi < 8; ++mi)
      #pragma unroll
      for (int v = 0; v < 4; ++v) rs[mi][v] += __shfl_xor(rs[mi][v], m);
  if (r16 == 0) {
    #pragma unroll
    for (int mi = 0; mi < 8; ++mi)
      #pragma unroll
      for (int v = 0; v < 4; ++v)
        atomicAdd(&dsum[wr*128 + mi*16 + quad*4 + v], rs[mi][v]);
  }
  __syncthreads();
  if (t < 256) atomicAdd(&denom[(size_t)(m0 + t) * 16 + (bn >> 4)], dsum[t]);
}

// ---------------------------------------------------------------------------
// GEMM2: out[b,j] += (1/denom[b,sp]) * sum_n E[b,n] vT[j,n], split-K = head.
// 256x256 tile, 256 blocks (1/CU), bijective XCD swizzle (2 heads per XCD).
// ---------------------------------------------------------------------------
__global__ __launch_bounds__(512, 2) void k_gemm2(
    const unsigned short* __restrict__ E, const unsigned short* __restrict__ Vt,
    float* __restrict__ out, const float* __restrict__ denom) {
  __shared__ __align__(16) unsigned short As[2 * 16384];
  __shared__ __align__(16) unsigned short Bs[2 * 16384];
  const int t = threadIdx.x;
  const int lb = (blockIdx.x & 7) * 32 + (blockIdx.x >> 3);  // bijective, 256 blocks
  const int bm = lb & 3, bn = (lb >> 2) & 3, sp = lb >> 4;
  const int m0 = bm << 8, n0 = bn << 8;
  f32x4 acc[8][4] = {};
  gemm_core(E, Vt, NKH, NKH, m0, n0, (size_t)sp * 4096, 4096 / 64, As, Bs, acc);
  const int lane = t & 63, w = t >> 6, wr = w >> 2, wc = w & 3;
  const int r16 = lane & 15, quad = lane >> 4;
  #pragma unroll
  for (int mi = 0; mi < 8; ++mi) {
    float rr[4];
    #pragma unroll
    for (int v = 0; v < 4; ++v) {
      int row = m0 + wr*128 + mi*16 + quad*4 + v;
      rr[v] = 1.0f / denom[(size_t)row * 16 + sp];
    }
    #pragma unroll
    for (int ni = 0; ni < 4; ++ni) {
      #pragma unroll
      for (int v = 0; v < 4; ++v) {
        int row = m0 + wr*128 + mi*16 + quad*4 + v;
        int col = n0 + wc*64 + ni*16 + r16;
        unsafeAtomicAdd(&out[(size_t)row * HID + col], acc[mi][ni][v] * rr[v]);
      }
    }
  }
}

extern "C" void kernel_launch(void* const* d_in, const int* in_sizes, int n_in,
                              void* d_out, int out_size, void* d_ws, size_t ws_size,
                              hipStream_t stream) {
  (void)in_sizes; (void)n_in; (void)out_size; (void)ws_size;
  const float* x      = (const float*)d_in[0];
  const float* keys   = (const float*)d_in[1];
  const float* values = (const float*)d_in[2];
  float* out = (float*)d_out;

  // ws: E [1024*65536] bf16 | B2 [65536*1024] bf16 (Kb', later vT') |
  //     Xb [1024*1024] bf16 | denom [1024*16] f32   (~270 MB)
  unsigned short* E  = (unsigned short*)d_ws;
  unsigned short* B2 = E + (size_t)BATCH * NKH;
  unsigned short* Xb = B2 + (size_t)NKH * DIM;
  float* denom = (float*)(Xb + (size_t)BATCH * DIM);

  k_cast_all<<<(KEY_GROUPS + X_GROUPS + DN_GROUPS) / 256, 256, 0, stream>>>(
      keys, x, B2, Xb, denom);
  k_gemm1_exp<<<(BATCH / 256) * (NKH / 256), 512, 0, stream>>>(Xb, B2, E, denom);
  // B2 free after gemm1: reuse for head-major vT; also zeroes out for gemm2
  k_fuse_vt<<<16384 + 1024, 256, 0, stream>>>(values, B2, out);
  k_gemm2<<<(BATCH / 256) * (HID / 256) * 16, 512, 0, stream>>>(E, B2, out, denom);
}